// Round 4
// baseline (104.299 us; speedup 1.0000x reference)
//
#include <hip/hip_runtime.h>

// Per-a batched GEMM, each H element read exactly once:
//   Yre[b,k] = sum_j Xre[b,j]*hr1[a,j,k] + Xim[b,j]*hi1[a,j,k]
//   Yim[b,k] = sum_j Xre[b,j]*hi2[a,j,k] + Xim[b,j]*hr2[a,j,k]
//
// Block = one 'a', 256 threads = 4 waves: wave = (ch = w>>1, jh = w&1).
//   Lane: m = lane>>5 (matrix of pair / x channel), kg = lane&31 -> k0=4*kg.
//   Lane accumulates all 16 b for its 4 k (64 VGPR acc).
// Round-4 changes vs round-3:
//   * x LDS reads register-double-buffered (xA/xB ping-pong) -> FMA stream
//     never waits on current-j ds_read (only on 1-iter-old ones).
//   * staging writes XOR-swizzled: elem (j,c,b) at j*32+((c*16+b)^key(j)),
//     key(j)=((j>>4)&3)<<2. Write key is thread-invariant (free); spreads
//     64 lanes across 32 banks (was 8-way conflict). Reads stay broadcast.
//   * H prefetch ring issued BEFORE __syncthreads (rides out staging).

__global__ __launch_bounds__(256, 4)
void hmat_kernel(const float* __restrict__ x,
                 const float* __restrict__ hr1,
                 const float* __restrict__ hi1,
                 const float* __restrict__ hr2,
                 const float* __restrict__ hi2,
                 const int* __restrict__ perm,
                 float* __restrict__ out) {
  __shared__ float lds[4096];  // x stage [j][swizzled c*16+b]; then reduce buf
  const int a = blockIdx.x;
  const int t = threadIdx.x;

  const int w    = t >> 6;   // wave 0..3
  const int ch   = w >> 1;   // output channel
  const int jh   = w & 1;    // j half: [0,64) or [64,128)
  const int lane = t & 63;
  const int m    = lane >> 5;  // matrix of the pair; x channel c == m
  const int kg   = lane & 31;
  const int k0   = kg * 4;

  const float* __restrict__ Hm =
      (ch == 0) ? (m == 0 ? hr1 : hi1) : (m == 0 ? hi2 : hr2);
  const float* __restrict__ hp =
      Hm + (size_t)a * 16384 + (size_t)jh * 8192 + k0;

  // ---- stage permuted x into LDS (swizzled), H pf issued pre-barrier ----
  {
    const int b    = t >> 4;        // 0..15
    const int c    = (t >> 3) & 1;  // 0..1
    const int jg   = (t >> 1) & 3;  // 0..3
    const int half = t & 1;         // 0..1
    const int row  = perm[a * 4 + jg];
    const float4* src =
        (const float4*)(x + ((size_t)(b * 2 + c) * 4096 + (size_t)row) * 32 +
                        half * 16);
    float4 v0 = src[0], v1 = src[1], v2 = src[2], v3 = src[3];
    // write key is thread-invariant: key = ((j>>4)&3)<<2, j>>4 == jg*2+half
    const int col = (c * 16 + b) ^ ((((jg << 1) | half) & 3) << 2);
    const int jb  = jg * 32 + half * 16;
#define PUTX(V, Q)                             \
  lds[(jb + (Q)*4 + 0) * 32 + col] = (V).x;    \
  lds[(jb + (Q)*4 + 1) * 32 + col] = (V).y;    \
  lds[(jb + (Q)*4 + 2) * 32 + col] = (V).z;    \
  lds[(jb + (Q)*4 + 3) * 32 + col] = (V).w;
    PUTX(v0, 0) PUTX(v1, 1) PUTX(v2, 2) PUTX(v3, 3)
#undef PUTX
  }

  // H prefetch ring — independent of LDS, issue before barrier
  float4 pf0 = *(const float4*)(hp + 0 * 128);
  float4 pf1 = *(const float4*)(hp + 1 * 128);
  float4 pf2 = *(const float4*)(hp + 2 * 128);
  float4 pf3 = *(const float4*)(hp + 3 * 128);

  __syncthreads();

  const float* __restrict__ xp = lds + m * 16;  // + j*32, swizzled slots

  float4 acc[16];
#pragma unroll
  for (int i = 0; i < 16; ++i) acc[i] = make_float4(0.f, 0.f, 0.f, 0.f);

#define LOADX(X0, X1, X2, X3, J)                        \
  {                                                     \
    const float* xj = xp + (J) * 32;                    \
    const int key = (((J) >> 4) & 3) << 2;              \
    X0 = *(const float4*)(xj + (0 ^ key));              \
    X1 = *(const float4*)(xj + (4 ^ key));              \
    X2 = *(const float4*)(xj + (8 ^ key));              \
    X3 = *(const float4*)(xj + (12 ^ key));             \
  }

#define CONSUME(PF, XA, XB, XC, XD)                                        \
  {                                                                        \
    const float xs[16] = {XA.x, XA.y, XA.z, XA.w, XB.x, XB.y, XB.z, XB.w,  \
                          XC.x, XC.y, XC.z, XC.w, XD.x, XD.y, XD.z, XD.w}; \
    _Pragma("unroll") for (int bb = 0; bb < 16; ++bb) {                    \
      acc[bb].x = fmaf(xs[bb], (PF).x, acc[bb].x);                         \
      acc[bb].y = fmaf(xs[bb], (PF).y, acc[bb].y);                         \
      acc[bb].z = fmaf(xs[bb], (PF).z, acc[bb].z);                         \
      acc[bb].w = fmaf(xs[bb], (PF).w, acc[bb].w);                         \
    }                                                                      \
  }

  // j is the index within this wave's half; LDS base offset jh*2048 folded
  // into xp? No: xp indexes full 128-j buffer; this wave's rows are
  // jh*64 + j. Fold jh into a j offset:
  const int jofs = jh * 64;

  float4 xA0, xA1, xA2, xA3, xB0, xB1, xB2, xB3;
  LOADX(xA0, xA1, xA2, xA3, jofs + 0)

  for (int j4 = 0; j4 < 60; j4 += 4) {
    LOADX(xB0, xB1, xB2, xB3, jofs + j4 + 1)
    CONSUME(pf0, xA0, xA1, xA2, xA3)
    pf0 = *(const float4*)(hp + (j4 + 4) * 128);
    LOADX(xA0, xA1, xA2, xA3, jofs + j4 + 2)
    CONSUME(pf1, xB0, xB1, xB2, xB3)
    pf1 = *(const float4*)(hp + (j4 + 5) * 128);
    LOADX(xB0, xB1, xB2, xB3, jofs + j4 + 3)
    CONSUME(pf2, xA0, xA1, xA2, xA3)
    pf2 = *(const float4*)(hp + (j4 + 6) * 128);
    LOADX(xA0, xA1, xA2, xA3, jofs + j4 + 4)
    CONSUME(pf3, xB0, xB1, xB2, xB3)
    pf3 = *(const float4*)(hp + (j4 + 7) * 128);
  }
  // tail: j = 60..63, no further H loads (avoid OOB past last matrix)
  LOADX(xB0, xB1, xB2, xB3, jofs + 61)
  CONSUME(pf0, xA0, xA1, xA2, xA3)
  LOADX(xA0, xA1, xA2, xA3, jofs + 62)
  CONSUME(pf1, xB0, xB1, xB2, xB3)
  LOADX(xB0, xB1, xB2, xB3, jofs + 63)
  CONSUME(pf2, xA0, xA1, xA2, xA3)
  CONSUME(pf3, xB0, xB1, xB2, xB3)
#undef LOADX
#undef CONSUME

  // ---- fold the two matrix-halves: lane p += lane p^32 ----
#pragma unroll
  for (int bb = 0; bb < 16; ++bb) {
    acc[bb].x += __shfl_xor(acc[bb].x, 32, 64);
    acc[bb].y += __shfl_xor(acc[bb].y, 32, 64);
    acc[bb].z += __shfl_xor(acc[bb].z, 32, 64);
    acc[bb].w += __shfl_xor(acc[bb].w, 32, 64);
  }

  // ---- reduce the two j-halves via LDS (reuse x buffer) ----
  __syncthreads();  // all waves done reading x
  if (jh == 1 && m == 0) {
#pragma unroll
    for (int bb = 0; bb < 16; ++bb)
      *(float4*)&lds[ch * 2048 + bb * 128 + k0] = acc[bb];
  }
  __syncthreads();
  if (jh == 0 && m == 0) {
#pragma unroll
    for (int bb = 0; bb < 16; ++bb) {
      const float4 o = *(const float4*)&lds[ch * 2048 + bb * 128 + k0];
      float4 r;
      r.x = acc[bb].x + o.x;
      r.y = acc[bb].y + o.y;
      r.z = acc[bb].z + o.z;
      r.w = acc[bb].w + o.w;
      *(float4*)(out + (size_t)(bb * 2 + ch) * 131072 + (size_t)a * 128 + k0) =
          r;
    }
  }
}

extern "C" void kernel_launch(void* const* d_in, const int* in_sizes, int n_in,
                              void* d_out, int out_size, void* d_ws, size_t ws_size,
                              hipStream_t stream) {
  const float* x   = (const float*)d_in[0];
  const float* hr1 = (const float*)d_in[1];
  const float* hi1 = (const float*)d_in[2];
  const float* hr2 = (const float*)d_in[3];
  const float* hi2 = (const float*)d_in[4];
  const int* perm  = (const int*)d_in[5];
  float* out = (float*)d_out;

  hipLaunchKernelGGL(hmat_kernel, dim3(1024), dim3(256), 0, stream,
                     x, hr1, hi1, hr2, hi2, perm, out);
}

// Round 5
// 84.534 us; speedup vs baseline: 1.2338x; 1.2338x over previous
//
#include <hip/hip_runtime.h>

// Per-a batched GEMM, each H element read exactly once:
//   Yre[b,k] = sum_j Xre[b,j]*hr1[a,j,k] + Xim[b,j]*hi1[a,j,k]
//   Yim[b,k] = sum_j Xre[b,j]*hi2[a,j,k] + Xim[b,j]*hr2[a,j,k]
//
// Block = one 'a', 256 threads = 4 waves: wave = (ch = w>>1, jh = w&1).
//   Lane: m = lane>>5 (matrix of pair / x channel), kg = lane&31 -> k0=4*kg.
//   Lane accumulates all 16 b for its 4 k (64 VGPR acc).
//
// Round-5 = round-3 loop (immediate-consume 4-deep H ring; NO x reg
// double-buffer -- round-4's ping-pong spilled acc to scratch: WRITE_SIZE
// 204 MB vs 20 MB, dur 57->104 us) + the two verified-cheap round-4 fixes:
//   * staging writes XOR-swizzled (SQ_LDS_BANK_CONFLICT 917K -> 131K):
//     elem (j,c,b) at j*32 + ((c*16+b) ^ key(j)), key(j)=((j>>4)&3)<<2.
//     Write key is thread-invariant; reads permute float4 slots by key.
//   * H prefetch ring issued BEFORE __syncthreads (hides cold HBM latency
//     under the staging writes + barrier drain).

__global__ __launch_bounds__(256, 4)
void hmat_kernel(const float* __restrict__ x,
                 const float* __restrict__ hr1,
                 const float* __restrict__ hi1,
                 const float* __restrict__ hr2,
                 const float* __restrict__ hi2,
                 const int* __restrict__ perm,
                 float* __restrict__ out) {
  __shared__ float lds[4096];  // x stage [j][swizzled c*16+b]; then reduce buf
  const int a = blockIdx.x;
  const int t = threadIdx.x;

  const int w    = t >> 6;   // wave 0..3
  const int ch   = w >> 1;   // output channel
  const int jh   = w & 1;    // j half: [0,64) or [64,128)
  const int lane = t & 63;
  const int m    = lane >> 5;  // matrix of the pair; x channel c == m
  const int kg   = lane & 31;
  const int k0   = kg * 4;

  const float* __restrict__ Hm =
      (ch == 0) ? (m == 0 ? hr1 : hi1) : (m == 0 ? hi2 : hr2);
  const float* __restrict__ hp =
      Hm + (size_t)a * 16384 + (size_t)jh * 8192 + k0;

  // ---- stage permuted x into LDS (swizzled) ----
  {
    const int b    = t >> 4;        // 0..15
    const int c    = (t >> 3) & 1;  // 0..1
    const int jg   = (t >> 1) & 3;  // 0..3
    const int half = t & 1;         // 0..1
    const int row  = perm[a * 4 + jg];
    const float4* src =
        (const float4*)(x + ((size_t)(b * 2 + c) * 4096 + (size_t)row) * 32 +
                        half * 16);
    float4 v0 = src[0], v1 = src[1], v2 = src[2], v3 = src[3];
    // thread-invariant write key: j>>4 == jg*2+half for this thread's rows
    const int col = (c * 16 + b) ^ ((((jg << 1) | half) & 3) << 2);
    const int jb  = jg * 32 + half * 16;
#define PUTX(V, Q)                             \
  lds[(jb + (Q)*4 + 0) * 32 + col] = (V).x;    \
  lds[(jb + (Q)*4 + 1) * 32 + col] = (V).y;    \
  lds[(jb + (Q)*4 + 2) * 32 + col] = (V).z;    \
  lds[(jb + (Q)*4 + 3) * 32 + col] = (V).w;
    PUTX(v0, 0) PUTX(v1, 1) PUTX(v2, 2) PUTX(v3, 3)
#undef PUTX
  }

  // H prefetch ring -- independent of LDS, issue before the barrier so the
  // cold HBM latency rides out under staging + barrier drain.
  float4 pf0 = *(const float4*)(hp + 0 * 128);
  float4 pf1 = *(const float4*)(hp + 1 * 128);
  float4 pf2 = *(const float4*)(hp + 2 * 128);
  float4 pf3 = *(const float4*)(hp + 3 * 128);

  __syncthreads();

  const float* __restrict__ xp = lds + m * 16;  // + J*32, swizzled slots
  const int jofs = jh * 64;                     // this wave's global j base

  float4 acc[16];
#pragma unroll
  for (int i = 0; i < 16; ++i) acc[i] = make_float4(0.f, 0.f, 0.f, 0.f);

  // Reads: b-group d lives at float4 slot ((d ^ (key>>2))<<2), key per j.
#define CONSUME(PF, J)                                                     \
  {                                                                        \
    const float* xj = xp + (J) * 32;                                       \
    const int key = (((J) >> 4) & 3) << 2;                                 \
    const float4 xa = *(const float4*)(xj + (0 ^ key));                    \
    const float4 xb = *(const float4*)(xj + (4 ^ key));                    \
    const float4 xc = *(const float4*)(xj + (8 ^ key));                    \
    const float4 xd = *(const float4*)(xj + (12 ^ key));                   \
    const float xs[16] = {xa.x, xa.y, xa.z, xa.w, xb.x, xb.y, xb.z, xb.w,  \
                          xc.x, xc.y, xc.z, xc.w, xd.x, xd.y, xd.z, xd.w}; \
    _Pragma("unroll") for (int bb = 0; bb < 16; ++bb) {                    \
      acc[bb].x = fmaf(xs[bb], (PF).x, acc[bb].x);                         \
      acc[bb].y = fmaf(xs[bb], (PF).y, acc[bb].y);                         \
      acc[bb].z = fmaf(xs[bb], (PF).z, acc[bb].z);                         \
      acc[bb].w = fmaf(xs[bb], (PF).w, acc[bb].w);                         \
    }                                                                      \
  }

  for (int j4 = 0; j4 < 60; j4 += 4) {
    CONSUME(pf0, jofs + j4 + 0); pf0 = *(const float4*)(hp + (j4 + 4) * 128);
    CONSUME(pf1, jofs + j4 + 1); pf1 = *(const float4*)(hp + (j4 + 5) * 128);
    CONSUME(pf2, jofs + j4 + 2); pf2 = *(const float4*)(hp + (j4 + 6) * 128);
    CONSUME(pf3, jofs + j4 + 3); pf3 = *(const float4*)(hp + (j4 + 7) * 128);
  }
  CONSUME(pf0, jofs + 60);
  CONSUME(pf1, jofs + 61);
  CONSUME(pf2, jofs + 62);
  CONSUME(pf3, jofs + 63);
#undef CONSUME

  // ---- fold the two matrix-halves: lane p += lane p^32 ----
#pragma unroll
  for (int bb = 0; bb < 16; ++bb) {
    acc[bb].x += __shfl_xor(acc[bb].x, 32, 64);
    acc[bb].y += __shfl_xor(acc[bb].y, 32, 64);
    acc[bb].z += __shfl_xor(acc[bb].z, 32, 64);
    acc[bb].w += __shfl_xor(acc[bb].w, 32, 64);
  }

  // ---- reduce the two j-halves via LDS (reuse x buffer) ----
  __syncthreads();  // all waves done reading x
  if (jh == 1 && m == 0) {
#pragma unroll
    for (int bb = 0; bb < 16; ++bb)
      *(float4*)&lds[ch * 2048 + bb * 128 + k0] = acc[bb];
  }
  __syncthreads();
  if (jh == 0 && m == 0) {
#pragma unroll
    for (int bb = 0; bb < 16; ++bb) {
      const float4 o = *(const float4*)&lds[ch * 2048 + bb * 128 + k0];
      float4 r;
      r.x = acc[bb].x + o.x;
      r.y = acc[bb].y + o.y;
      r.z = acc[bb].z + o.z;
      r.w = acc[bb].w + o.w;
      *(float4*)(out + (size_t)(bb * 2 + ch) * 131072 + (size_t)a * 128 + k0) =
          r;
    }
  }
}

extern "C" void kernel_launch(void* const* d_in, const int* in_sizes, int n_in,
                              void* d_out, int out_size, void* d_ws, size_t ws_size,
                              hipStream_t stream) {
  const float* x   = (const float*)d_in[0];
  const float* hr1 = (const float*)d_in[1];
  const float* hi1 = (const float*)d_in[2];
  const float* hr2 = (const float*)d_in[3];
  const float* hi2 = (const float*)d_in[4];
  const int* perm  = (const int*)d_in[5];
  float* out = (float*)d_out;

  hipLaunchKernelGGL(hmat_kernel, dim3(1024), dim3(256), 0, stream,
                     x, hr1, hi1, hr2, hi2, perm, out);
}

// Round 6
// 82.939 us; speedup vs baseline: 1.2575x; 1.0192x over previous
//
#include <hip/hip_runtime.h>

// Per-a batched GEMM, each H element fetched exactly once:
//   Yre[b,k] = sum_j Xre[b,j]*hr1[a,j,k] + Xim[b,j]*hi1[a,j,k]
//   Yim[b,k] = sum_j Xre[b,j]*hi2[a,j,k] + Xim[b,j]*hr2[a,j,k]
//
// Round-6 structure (vs round-3's 57us):
//   Block = one 'a', 256 threads = 4 waves: wave = (ch = w>>1, m = w&1)
//     where m picks the matrix of the channel's pair (x channel c == m).
//   Lane: bh = lane>>5 (b half: 8 b), kg = lane&31 -> k0 = 4*kg.
//   acc = 8 b x 4 k = 32 VGPR (was 64) -> freed regs fund an 8-deep H
//   prefetch ring (was 4; ring-4 = ~512 own-issue cyc < ~900 cyc HBM lat).
//   Wave covers ALL 128 j of its matrix; bh=0/bh=1 lanes read identical H
//   addresses (one coalesced request) -> every H float4 still read once.
//   Epilogue: m=1 wave stages partials in LDS, m=0 wave adds and stores.
//   Staging conflict fixed by thread-bit re-slice: col = c*16+b spans all
//   32 banks within a wave (write key static; read path plain, no XOR --
//   round-4/5's runtime-XOR reads spilled acc: WRITE_SIZE 100-204 MB).

__global__ __launch_bounds__(256, 4)
void hmat_kernel(const float* __restrict__ x,
                 const float* __restrict__ hr1,
                 const float* __restrict__ hi1,
                 const float* __restrict__ hr2,
                 const float* __restrict__ hi2,
                 const int* __restrict__ perm,
                 float* __restrict__ out) {
  __shared__ float lds[4096];  // x stage [j=128][col=c*16+b]; then reduce buf
  const int a = blockIdx.x;
  const int t = threadIdx.x;

  const int w    = t >> 6;     // wave 0..3
  const int ch   = w >> 1;     // output channel
  const int m    = w & 1;      // matrix of the pair; x channel c == m
  const int lane = t & 63;
  const int bh   = lane >> 5;  // b half: 0 -> b0..7, 1 -> b8..15
  const int kg   = lane & 31;
  const int k0   = kg * 4;

  const float* __restrict__ Hm =
      (ch == 0) ? (m == 0 ? hr1 : hi1) : (m == 0 ? hi2 : hr2);
  const float* __restrict__ hp = Hm + (size_t)a * 16384 + k0;

  // ---- stage permuted x into LDS ----
  // thread fields: c = t&1, b = (t>>1)&15, q = t>>5 (jg = q>>1, half = q&1)
  // -> within any wave, col = c*16+b covers all 32 banks (2 lanes/bank at
  //    different rows = free). Each thread loads 16 consecutive floats
  //    (one 64B line) and writes 16 rows of its column.
  {
    const int c    = t & 1;
    const int b    = (t >> 1) & 15;
    const int q    = t >> 5;
    const int jg   = q >> 1;
    const int half = q & 1;
    const int row  = perm[a * 4 + jg];
    const float4* src =
        (const float4*)(x + ((size_t)(b * 2 + c) * 4096 + (size_t)row) * 32 +
                        half * 16);
    float4 v0 = src[0], v1 = src[1], v2 = src[2], v3 = src[3];
    const int col = c * 16 + b;
    const int jb  = jg * 32 + half * 16;
#define PUTX(V, Q)                            \
  lds[(jb + (Q)*4 + 0) * 32 + col] = (V).x;   \
  lds[(jb + (Q)*4 + 1) * 32 + col] = (V).y;   \
  lds[(jb + (Q)*4 + 2) * 32 + col] = (V).z;   \
  lds[(jb + (Q)*4 + 3) * 32 + col] = (V).w;
    PUTX(v0, 0) PUTX(v1, 1) PUTX(v2, 2) PUTX(v3, 3)
#undef PUTX
  }

  // 8-deep H prefetch ring, issued before the barrier (independent of LDS;
  // cold HBM latency rides out under staging + barrier drain).
  float4 pf0 = *(const float4*)(hp + 0 * 128);
  float4 pf1 = *(const float4*)(hp + 1 * 128);
  float4 pf2 = *(const float4*)(hp + 2 * 128);
  float4 pf3 = *(const float4*)(hp + 3 * 128);
  float4 pf4 = *(const float4*)(hp + 4 * 128);
  float4 pf5 = *(const float4*)(hp + 5 * 128);
  float4 pf6 = *(const float4*)(hp + 6 * 128);
  float4 pf7 = *(const float4*)(hp + 7 * 128);

  __syncthreads();

  const float* __restrict__ xp = lds + m * 16 + bh * 8;  // + J*32

  float4 acc[8];
#pragma unroll
  for (int i = 0; i < 8; ++i) acc[i] = make_float4(0.f, 0.f, 0.f, 0.f);

#define CONSUME(PF, J)                                                 \
  {                                                                    \
    const float4 xa = *(const float4*)(xp + (J) * 32);                 \
    const float4 xb = *(const float4*)(xp + (J) * 32 + 4);             \
    const float xs[8] = {xa.x, xa.y, xa.z, xa.w,                       \
                         xb.x, xb.y, xb.z, xb.w};                      \
    _Pragma("unroll") for (int bb = 0; bb < 8; ++bb) {                 \
      acc[bb].x = fmaf(xs[bb], (PF).x, acc[bb].x);                     \
      acc[bb].y = fmaf(xs[bb], (PF).y, acc[bb].y);                     \
      acc[bb].z = fmaf(xs[bb], (PF).z, acc[bb].z);                     \
      acc[bb].w = fmaf(xs[bb], (PF).w, acc[bb].w);                     \
    }                                                                  \
  }

  for (int j8 = 0; j8 < 120; j8 += 8) {
    CONSUME(pf0, j8 + 0); pf0 = *(const float4*)(hp + (j8 +  8) * 128);
    CONSUME(pf1, j8 + 1); pf1 = *(const float4*)(hp + (j8 +  9) * 128);
    CONSUME(pf2, j8 + 2); pf2 = *(const float4*)(hp + (j8 + 10) * 128);
    CONSUME(pf3, j8 + 3); pf3 = *(const float4*)(hp + (j8 + 11) * 128);
    CONSUME(pf4, j8 + 4); pf4 = *(const float4*)(hp + (j8 + 12) * 128);
    CONSUME(pf5, j8 + 5); pf5 = *(const float4*)(hp + (j8 + 13) * 128);
    CONSUME(pf6, j8 + 6); pf6 = *(const float4*)(hp + (j8 + 14) * 128);
    CONSUME(pf7, j8 + 7); pf7 = *(const float4*)(hp + (j8 + 15) * 128);
  }
  CONSUME(pf0, 120);
  CONSUME(pf1, 121);
  CONSUME(pf2, 122);
  CONSUME(pf3, 123);
  CONSUME(pf4, 124);
  CONSUME(pf5, 125);
  CONSUME(pf6, 126);
  CONSUME(pf7, 127);
#undef CONSUME

  // ---- reduce across the two m-waves per channel via LDS ----
  __syncthreads();  // all waves done reading x
  if (m == 1) {
#pragma unroll
    for (int bb = 0; bb < 8; ++bb)
      *(float4*)&lds[ch * 2048 + (bh * 8 + bb) * 128 + k0] = acc[bb];
  }
  __syncthreads();
  if (m == 0) {
#pragma unroll
    for (int bb = 0; bb < 8; ++bb) {
      const float4 o = *(const float4*)&lds[ch * 2048 + (bh * 8 + bb) * 128 + k0];
      const int b = bh * 8 + bb;
      float4 r;
      r.x = acc[bb].x + o.x;
      r.y = acc[bb].y + o.y;
      r.z = acc[bb].z + o.z;
      r.w = acc[bb].w + o.w;
      *(float4*)(out + (size_t)(b * 2 + ch) * 131072 + (size_t)a * 128 + k0) =
          r;
    }
  }
}

extern "C" void kernel_launch(void* const* d_in, const int* in_sizes, int n_in,
                              void* d_out, int out_size, void* d_ws, size_t ws_size,
                              hipStream_t stream) {
  const float* x   = (const float*)d_in[0];
  const float* hr1 = (const float*)d_in[1];
  const float* hi1 = (const float*)d_in[2];
  const float* hr2 = (const float*)d_in[3];
  const float* hi2 = (const float*)d_in[4];
  const int* perm  = (const int*)d_in[5];
  float* out = (float*)d_out;

  hipLaunchKernelGGL(hmat_kernel, dim3(1024), dim3(256), 0, stream,
                     x, hr1, hi1, hr2, hi2, perm, out);
}

// Round 7
// 82.008 us; speedup vs baseline: 1.2718x; 1.0114x over previous
//
#include <hip/hip_runtime.h>

// Per-a batched GEMM, each H element fetched exactly once:
//   Yre[b,k] = sum_j Xre[b,j]*hr1[a,j,k] + Xim[b,j]*hi1[a,j,k]
//   Yim[b,k] = sum_j Xre[b,j]*hi2[a,j,k] + Xim[b,j]*hr2[a,j,k]
//
// Round-7 = round-6 mapping with ALL prefetch moved AFTER __syncthreads.
// Evidence: r3 (pf after barrier) was WRITE-clean (20 MB) at 57us; r4/r5/r6
// (pf before barrier) all show ~80-180 MB of scratch writebacks (WRITE_SIZE
// 99-204 MB vs 21 MB of real output) and 83-104us. The barrier drains vmcnt
// anyway, so pre-barrier issue bought nothing and cost co-liveness of the
// staging set + ring -> spill. Keep r6's verified wins: wave=(ch,m) mapping
// (32-reg acc), conflict-free staging (SQ_LDS_BANK_CONFLICT == 0), 8-deep
// ring funded by the halved accumulator (live ~85 regs < 128 cap).

__global__ __launch_bounds__(256, 4)
void hmat_kernel(const float* __restrict__ x,
                 const float* __restrict__ hr1,
                 const float* __restrict__ hi1,
                 const float* __restrict__ hr2,
                 const float* __restrict__ hi2,
                 const int* __restrict__ perm,
                 float* __restrict__ out) {
  __shared__ float lds[4096];  // x stage [j=128][col=c*16+b]; then reduce buf
  const int a = blockIdx.x;
  const int t = threadIdx.x;

  const int w    = t >> 6;     // wave 0..3
  const int ch   = w >> 1;     // output channel
  const int m    = w & 1;      // matrix of the pair; x channel c == m
  const int lane = t & 63;
  const int bh   = lane >> 5;  // b half: 0 -> b0..7, 1 -> b8..15
  const int kg   = lane & 31;
  const int k0   = kg * 4;

  const float* __restrict__ Hm =
      (ch == 0) ? (m == 0 ? hr1 : hi1) : (m == 0 ? hi2 : hr2);
  const float* __restrict__ hp = Hm + (size_t)a * 16384 + k0;

  // ---- stage permuted x into LDS (conflict-free: col spans 32 banks) ----
  {
    const int c    = t & 1;
    const int b    = (t >> 1) & 15;
    const int q    = t >> 5;
    const int jg   = q >> 1;
    const int half = q & 1;
    const int row  = perm[a * 4 + jg];
    const float4* src =
        (const float4*)(x + ((size_t)(b * 2 + c) * 4096 + (size_t)row) * 32 +
                        half * 16);
    float4 v0 = src[0], v1 = src[1], v2 = src[2], v3 = src[3];
    const int col = c * 16 + b;
    const int jb  = jg * 32 + half * 16;
#define PUTX(V, Q)                            \
  lds[(jb + (Q)*4 + 0) * 32 + col] = (V).x;   \
  lds[(jb + (Q)*4 + 1) * 32 + col] = (V).y;   \
  lds[(jb + (Q)*4 + 2) * 32 + col] = (V).z;   \
  lds[(jb + (Q)*4 + 3) * 32 + col] = (V).w;
    PUTX(v0, 0) PUTX(v1, 1) PUTX(v2, 2) PUTX(v3, 3)
#undef PUTX
  }

  __syncthreads();

  // 8-deep H prefetch ring, issued AFTER the barrier (r3's clean pattern —
  // pre-barrier issue caused scratch spill, see header comment).
  float4 pf0 = *(const float4*)(hp + 0 * 128);
  float4 pf1 = *(const float4*)(hp + 1 * 128);
  float4 pf2 = *(const float4*)(hp + 2 * 128);
  float4 pf3 = *(const float4*)(hp + 3 * 128);
  float4 pf4 = *(const float4*)(hp + 4 * 128);
  float4 pf5 = *(const float4*)(hp + 5 * 128);
  float4 pf6 = *(const float4*)(hp + 6 * 128);
  float4 pf7 = *(const float4*)(hp + 7 * 128);

  const float* __restrict__ xp = lds + m * 16 + bh * 8;  // + J*32

  float4 acc[8];
#pragma unroll
  for (int i = 0; i < 8; ++i) acc[i] = make_float4(0.f, 0.f, 0.f, 0.f);

#define CONSUME(PF, J)                                                 \
  {                                                                    \
    const float4 xa = *(const float4*)(xp + (J) * 32);                 \
    const float4 xb = *(const float4*)(xp + (J) * 32 + 4);             \
    const float xs[8] = {xa.x, xa.y, xa.z, xa.w,                       \
                         xb.x, xb.y, xb.z, xb.w};                      \
    _Pragma("unroll") for (int bb = 0; bb < 8; ++bb) {                 \
      acc[bb].x = fmaf(xs[bb], (PF).x, acc[bb].x);                     \
      acc[bb].y = fmaf(xs[bb], (PF).y, acc[bb].y);                     \
      acc[bb].z = fmaf(xs[bb], (PF).z, acc[bb].z);                     \
      acc[bb].w = fmaf(xs[bb], (PF).w, acc[bb].w);                     \
    }                                                                  \
  }

  for (int j8 = 0; j8 < 120; j8 += 8) {
    CONSUME(pf0, j8 + 0); pf0 = *(const float4*)(hp + (j8 +  8) * 128);
    CONSUME(pf1, j8 + 1); pf1 = *(const float4*)(hp + (j8 +  9) * 128);
    CONSUME(pf2, j8 + 2); pf2 = *(const float4*)(hp + (j8 + 10) * 128);
    CONSUME(pf3, j8 + 3); pf3 = *(const float4*)(hp + (j8 + 11) * 128);
    CONSUME(pf4, j8 + 4); pf4 = *(const float4*)(hp + (j8 + 12) * 128);
    CONSUME(pf5, j8 + 5); pf5 = *(const float4*)(hp + (j8 + 13) * 128);
    CONSUME(pf6, j8 + 6); pf6 = *(const float4*)(hp + (j8 + 14) * 128);
    CONSUME(pf7, j8 + 7); pf7 = *(const float4*)(hp + (j8 + 15) * 128);
  }
  CONSUME(pf0, 120);
  CONSUME(pf1, 121);
  CONSUME(pf2, 122);
  CONSUME(pf3, 123);
  CONSUME(pf4, 124);
  CONSUME(pf5, 125);
  CONSUME(pf6, 126);
  CONSUME(pf7, 127);
#undef CONSUME

  // ---- reduce across the two m-waves per channel via LDS ----
  __syncthreads();  // all waves done reading x
  if (m == 1) {
#pragma unroll
    for (int bb = 0; bb < 8; ++bb)
      *(float4*)&lds[ch * 2048 + (bh * 8 + bb) * 128 + k0] = acc[bb];
  }
  __syncthreads();
  if (m == 0) {
#pragma unroll
    for (int bb = 0; bb < 8; ++bb) {
      const float4 o = *(const float4*)&lds[ch * 2048 + (bh * 8 + bb) * 128 + k0];
      const int b = bh * 8 + bb;
      float4 r;
      r.x = acc[bb].x + o.x;
      r.y = acc[bb].y + o.y;
      r.z = acc[bb].z + o.z;
      r.w = acc[bb].w + o.w;
      *(float4*)(out + (size_t)(b * 2 + ch) * 131072 + (size_t)a * 128 + k0) =
          r;
    }
  }
}

extern "C" void kernel_launch(void* const* d_in, const int* in_sizes, int n_in,
                              void* d_out, int out_size, void* d_ws, size_t ws_size,
                              hipStream_t stream) {
  const float* x   = (const float*)d_in[0];
  const float* hr1 = (const float*)d_in[1];
  const float* hi1 = (const float*)d_in[2];
  const float* hr2 = (const float*)d_in[3];
  const float* hi2 = (const float*)d_in[4];
  const int* perm  = (const int*)d_in[5];
  float* out = (float*)d_out;

  hipLaunchKernelGGL(hmat_kernel, dim3(1024), dim3(256), 0, stream,
                     x, hr1, hi1, hr2, hi2, perm, out);
}